// Round 1
// baseline (160.042 us; speedup 1.0000x reference)
//
#include <hip/hip_runtime.h>
#include <hip/hip_bf16.h>
#include <stdint.h>

// Problem constants (B,T,C,E) = (4,2048,1024,8)
#define NB 4
#define NT 2048
#define NC 1024
#define NE 8
#define NTOK (NB * NT)   // 8192 tokens

// GEMM tiling
#define BM 64
#define BN 64
#define BK 32
#define LPAD 40          // LDS row stride in bf16 elems (80B -> breaks pow2 bank stride)

typedef __attribute__((ext_vector_type(4))) float floatx4;
typedef __attribute__((ext_vector_type(8))) __bf16 bf16x8;

__device__ __forceinline__ unsigned short f2bf(float f) {
    uint32_t u = __builtin_bit_cast(uint32_t, f);
    u += 0x7FFFu + ((u >> 16) & 1u);   // round-to-nearest-even
    return (unsigned short)(u >> 16);
}

__global__ void zero_counts_k(int* __restrict__ counts) {
    if (threadIdx.x < NE) counts[threadIdx.x] = 0;
}

// One wave per token: router logits -> softmax decision -> bucket (or zero output row).
__global__ __launch_bounds__(256) void router_k(
    const float* __restrict__ x, const float* __restrict__ Wr,
    const float* __restrict__ br, float* __restrict__ out,
    int* __restrict__ counts, int* __restrict__ buckets)
{
    const int wave = threadIdx.x >> 6;
    const int lane = threadIdx.x & 63;
    const int tok  = blockIdx.x * 4 + wave;

    const float4* xr = (const float4*)(x + (size_t)tok * NC);
    float4 xv[4];
#pragma unroll
    for (int j = 0; j < 4; ++j) xv[j] = xr[lane + 64 * j];

    float acc[NE];
#pragma unroll
    for (int e = 0; e < NE; ++e) {
        const float4* wr = (const float4*)(Wr + e * NC);
        float a = 0.f;
#pragma unroll
        for (int j = 0; j < 4; ++j) {
            float4 w = wr[lane + 64 * j];
            a += xv[j].x * w.x; a += xv[j].y * w.y;
            a += xv[j].z * w.z; a += xv[j].w * w.w;
        }
        acc[e] = a;
    }
    // 64-lane butterfly reduction for all 8 experts
#pragma unroll
    for (int off = 32; off >= 1; off >>= 1)
#pragma unroll
        for (int e = 0; e < NE; ++e) acc[e] += __shfl_xor(acc[e], off);

#pragma unroll
    for (int e = 0; e < NE; ++e) acc[e] += br[e];

    float lmax = acc[0]; int emax = 0;
#pragma unroll
    for (int e = 1; e < NE; ++e) if (acc[e] > lmax) { lmax = acc[e]; emax = e; }
    float S = 0.f;
#pragma unroll
    for (int e = 0; e < NE; ++e) S += expf(acc[e] - lmax);

    const bool routed = (S < 2.0f);   // gate_max = 1/S > 0.5
    if (routed) {
        if (lane == 0) {
            int pos = atomicAdd(&counts[emax], 1);
            buckets[emax * NTOK + pos] = tok;
        }
    } else {
        // unrouted token -> output row is zeros (d_out is poisoned, never re-poisoned)
        float4 z = make_float4(0.f, 0.f, 0.f, 0.f);
        float4* orow = (float4*)(out + (size_t)tok * NC);
#pragma unroll
        for (int j = 0; j < 4; ++j) orow[lane + 64 * j] = z;
    }
}

// Grouped GEMM: per expert e, rows = bucketed tokens, y = x @ We[e]^T + be[e].
// 4 waves in 2x2, each wave does 32x32 via 2x2 mfma_f32_16x16x32_bf16 frags.
__global__ __launch_bounds__(256) void moe_gemm_k(
    const float* __restrict__ x, const float* __restrict__ We,
    const float* __restrict__ be, float* __restrict__ out,
    const int* __restrict__ counts, const int* __restrict__ buckets)
{
    const int e   = blockIdx.z;
    const int cnt = counts[e];
    const int m0  = blockIdx.x * BM;
    if (m0 >= cnt) return;
    const int n0  = blockIdx.y * BN;

    __shared__ unsigned short As[BM * LPAD];
    __shared__ unsigned short Bs[BM * LPAD];

    const int tid  = threadIdx.x;
    const int srow = tid >> 2;          // 0..63 staging row
    const int scg  = (tid & 3) * 8;     // 0,8,16,24 staging col group

    const int mrow = m0 + srow;
    const int tokA = (mrow < cnt) ? buckets[e * NTOK + mrow] : -1;
    const float* xrow = x + (size_t)(tokA < 0 ? 0 : tokA) * NC;
    const float* wrow = We + ((size_t)e * NC + (n0 + srow)) * NC;

    const int wave = tid >> 6, lane = tid & 63;
    const int wm = (wave >> 1) * 32, wn = (wave & 1) * 32;
    const int fr = lane & 15;           // fragment row/col within 16
    const int fk = (lane >> 4) * 8;     // fragment k offset

    floatx4 acc[2][2];
#pragma unroll
    for (int m = 0; m < 2; ++m)
#pragma unroll
        for (int n = 0; n < 2; ++n) acc[m][n] = (floatx4)(0.0f);

    for (int k0 = 0; k0 < NC; k0 += BK) {
        float4 a0 = make_float4(0.f,0.f,0.f,0.f), a1 = a0;
        if (tokA >= 0) {
            a0 = *(const float4*)(xrow + k0 + scg);
            a1 = *(const float4*)(xrow + k0 + scg + 4);
        }
        float4 b0 = *(const float4*)(wrow + k0 + scg);
        float4 b1 = *(const float4*)(wrow + k0 + scg + 4);

        __syncthreads();   // previous iteration's frag reads done
        union { bf16x8 v; unsigned short s[8]; } pa, pb;
        pa.s[0] = f2bf(a0.x); pa.s[1] = f2bf(a0.y); pa.s[2] = f2bf(a0.z); pa.s[3] = f2bf(a0.w);
        pa.s[4] = f2bf(a1.x); pa.s[5] = f2bf(a1.y); pa.s[6] = f2bf(a1.z); pa.s[7] = f2bf(a1.w);
        pb.s[0] = f2bf(b0.x); pb.s[1] = f2bf(b0.y); pb.s[2] = f2bf(b0.z); pb.s[3] = f2bf(b0.w);
        pb.s[4] = f2bf(b1.x); pb.s[5] = f2bf(b1.y); pb.s[6] = f2bf(b1.z); pb.s[7] = f2bf(b1.w);
        *(bf16x8*)&As[srow * LPAD + scg] = pa.v;
        *(bf16x8*)&Bs[srow * LPAD + scg] = pb.v;
        __syncthreads();   // tiles ready

        bf16x8 af[2], bfr[2];
#pragma unroll
        for (int m = 0; m < 2; ++m)
            af[m] = *(const bf16x8*)&As[(wm + m * 16 + fr) * LPAD + fk];
#pragma unroll
        for (int n = 0; n < 2; ++n)
            bfr[n] = *(const bf16x8*)&Bs[(wn + n * 16 + fr) * LPAD + fk];
#pragma unroll
        for (int m = 0; m < 2; ++m)
#pragma unroll
            for (int n = 0; n < 2; ++n)
                acc[m][n] = __builtin_amdgcn_mfma_f32_16x16x32_bf16(af[m], bfr[n], acc[m][n], 0, 0, 0);
    }

    // Epilogue: D layout col=lane&15, row=(lane>>4)*4+reg (m89-verified)
    const int r4 = (lane >> 4) * 4;
#pragma unroll
    for (int m = 0; m < 2; ++m) {
        const int trowb = m0 + wm + m * 16 + r4;
#pragma unroll
        for (int j = 0; j < 4; ++j) {
            const int trow = trowb + j;
            if (trow < cnt) {
                const int tok = buckets[e * NTOK + trow];
#pragma unroll
                for (int n = 0; n < 2; ++n) {
                    const int d = n0 + wn + n * 16 + fr;
                    out[(size_t)tok * NC + d] = acc[m][n][j] + be[e * NC + d];
                }
            }
        }
    }
}

extern "C" void kernel_launch(void* const* d_in, const int* in_sizes, int n_in,
                              void* d_out, int out_size, void* d_ws, size_t ws_size,
                              hipStream_t stream)
{
    const float* x  = (const float*)d_in[0];
    const float* Wr = (const float*)d_in[1];
    const float* br = (const float*)d_in[2];
    const float* We = (const float*)d_in[3];
    const float* be = (const float*)d_in[4];
    float* out = (float*)d_out;

    int* counts  = (int*)d_ws;            // NE ints
    int* buckets = (int*)d_ws + 64;       // NE * NTOK ints (256B-aligned offset)

    hipLaunchKernelGGL(zero_counts_k, dim3(1), dim3(64), 0, stream, counts);
    hipLaunchKernelGGL(router_k, dim3(NTOK / 4), dim3(256), 0, stream,
                       x, Wr, br, out, counts, buckets);
    hipLaunchKernelGGL(moe_gemm_k, dim3(NTOK / BM, NC / BN, NE), dim3(256), 0, stream,
                       x, We, be, out, counts, buckets);
}